// Round 1
// baseline (141.954 us; speedup 1.0000x reference)
//
#include <hip/hip_runtime.h>
#include <hip/hip_bf16.h>

#define VOCAB 100000
#define DIM   128
#define BATCH 16384
#define KNEG  20

// One wave (64 lanes) per batch row b. Lane i holds float2 = row[2i..2i+1],
// so each 128-float embedding row is one coalesced dwordx2 load per wave.
__global__ __launch_bounds__(256) void skipgram_loss_kernel(
    const int*   __restrict__ target,
    const int*   __restrict__ context,
    const int*   __restrict__ neg_samples,
    const float* __restrict__ in_embed,
    const float* __restrict__ out_embed,
    float*       __restrict__ out)
{
    const int lane  = threadIdx.x & 63;
    const int wave  = threadIdx.x >> 6;
    const int wpb   = blockDim.x >> 6;                 // waves per block (4)
    const int gwave = blockIdx.x * wpb + wave;
    const int nwav  = gridDim.x * wpb;

    float acc = 0.0f;  // wave-uniform after butterflies; identical in all lanes

    for (int b = gwave; b < BATCH; b += nwav) {
        const int trow = target[b];
        const int crow = context[b];

        const float2 t2 = *(const float2*)(in_embed  + (size_t)trow * DIM + lane * 2);
        const float2 c2 = *(const float2*)(out_embed + (size_t)crow * DIM + lane * 2);

        float p[KNEG + 1];
        p[0] = t2.x * c2.x + t2.y * c2.y;

        // Issue all 20 negative-row loads before the reduces (ILP / latency hiding).
        #pragma unroll
        for (int k = 0; k < KNEG; ++k) {
            const int nrow = neg_samples[b * KNEG + k];
            const float2 n2 = *(const float2*)(out_embed + (size_t)nrow * DIM + lane * 2);
            p[k + 1] = t2.x * n2.x + t2.y * n2.y;
        }

        #pragma unroll
        for (int k = 0; k < KNEG + 1; ++k) {
            float v = p[k];
            #pragma unroll
            for (int m = 1; m < 64; m <<= 1)
                v += __shfl_xor(v, m, 64);
            // v = full dot product, identical in all 64 lanes now.
            const float x  = (k == 0) ? v : -v;   // pos: ls(score); neg: ls(-score)
            // stable log_sigmoid(x) = min(x,0) - log1p(exp(-|x|))
            const float ls = fminf(x, 0.0f) - __logf(1.0f + __expf(-fabsf(x)));
            acc += ls;  // same value in every lane (wave-uniform)
        }
    }

    // Block reduction: lane 0 of each wave contributes its (wave-uniform) acc.
    __shared__ float smem[8];
    if (lane == 0) smem[wave] = acc;
    __syncthreads();
    if (threadIdx.x == 0) {
        float tot = 0.0f;
        for (int w = 0; w < wpb; ++w) tot += smem[w];
        atomicAdd(out, -tot * (1.0f / (float)BATCH));
    }
}

extern "C" void kernel_launch(void* const* d_in, const int* in_sizes, int n_in,
                              void* d_out, int out_size, void* d_ws, size_t ws_size,
                              hipStream_t stream) {
    const int*   target      = (const int*)  d_in[0];
    const int*   context     = (const int*)  d_in[1];
    const int*   neg_samples = (const int*)  d_in[2];
    const float* in_embed    = (const float*)d_in[3];
    const float* out_embed   = (const float*)d_in[4];
    float*       out         = (float*)d_out;

    // d_out is poisoned (0xAA) before every launch — zero it (capture-safe).
    hipMemsetAsync(out, 0, sizeof(float), stream);

    // 1024 blocks x 4 waves = 4096 waves -> 4 rows per wave.
    skipgram_loss_kernel<<<1024, 256, 0, stream>>>(
        target, context, neg_samples, in_embed, out_embed, out);
}